// Round 2
// baseline (24.452 us; speedup 1.0000x reference)
//
#include <hip/hip_runtime.h>

// Problem constants (fixed by reference setup_inputs):
//   B=64, IN=512, OUT=512, K=2, KK=4, T=IN*OUT=262144, TPO=T/OUT=512
constexpr int B    = 64;
constexpr int IN   = 512;
constexpr int OUT  = 512;
constexpr int T    = IN * OUT;
constexpr int TPO  = T / OUT;     // 512 tables per output feature
constexpr int TPW  = TPO / 4;     // 128 tables per wave-group
constexpr int PAD  = B + 1;       // 65: LDS row stride (conflict-free)

// Transform lut_weights[t][4] -> bilinear coefficients (A,B,C,D):
// per_table = A + B*x0 + C*x1 + D*x0*x1
__global__ void lut_coeff_kernel(const float4* __restrict__ lut,
                                 float4* __restrict__ coeff) {
    int t = blockIdx.x * blockDim.x + threadIdx.x;
    if (t < T) {
        float4 w = lut[t];
        float4 c;
        c.x = ( w.x + w.y + w.z + w.w) * 0.25f;   // A
        c.y = (-w.x + w.y - w.z + w.w) * 0.25f;   // B (codes bit0 -> x0)
        c.z = (-w.x - w.y + w.z + w.w) * 0.25f;   // C (codes bit1 -> x1)
        c.w = ( w.x - w.y - w.z + w.w) * 0.25f;   // D (x0*x1)
        coeff[t] = c;
    }
}

// One block = 512 threads = 8 waves, handles 2 output features.
// lane (tid&63) = batch index; wave-group (g&3) covers 128 tables.
// Static LDS (>64KB is fine on gfx950 when static — 160 KiB/CU):
//   xs[IN][65] transposed input: gather reads xs[idx*65+lane] hit banks
//   (idx*65+lane)%32 -> 2-way aliasing only (free); staging writes with
//   consecutive-lane consecutive-idx stride 65 cycle all banks (free).
template <bool USE_COEFF>
__global__ __launch_bounds__(512, 1)
void lut_main_kernel(const float* __restrict__ input,   // [B][IN]
                     const int*   __restrict__ mask,    // [T*2]
                     const float4* __restrict__ tab,    // coeff or raw lut
                     const float* __restrict__ bias,    // [OUT]
                     float* __restrict__ out) {         // [B][OUT]
    __shared__ float xs[IN * PAD];    // 130 KB
    __shared__ float red[8 * 64];     // 2 KB

    const int tid = threadIdx.x;

    // Stage input transposed: xs[i*65 + b] = input[b*IN + i].
    // Consecutive threads -> consecutive global addrs (coalesced).
    for (int f = tid; f < B * IN; f += 512) {
        int b = f >> 9;        // f / IN  (IN==512)
        int i = f & (IN - 1);  // f % IN
        xs[i * PAD + b] = input[f];
    }
    __syncthreads();

    const int b  = tid & 63;            // batch = lane
    const int g  = tid >> 6;            // wave 0..7
    const int o  = blockIdx.x * 2 + (g >> 2);
    const int t0 = o * TPO + (g & 3) * TPW;

    const int2*   m2 = reinterpret_cast<const int2*>(mask) + t0;
    const float4* w4 = tab + t0;

    float acc = 0.0f;
#pragma unroll 8
    for (int j = 0; j < TPW; ++j) {
        const int2   m = m2[j];   // wave-uniform -> broadcast load
        const float4 w = w4[j];   // wave-uniform -> broadcast load
        float A, Bc, Cc, Dd;
        if constexpr (USE_COEFF) {
            A = w.x; Bc = w.y; Cc = w.z; Dd = w.w;
        } else {
            A  = ( w.x + w.y + w.z + w.w) * 0.25f;
            Bc = (-w.x + w.y - w.z + w.w) * 0.25f;
            Cc = (-w.x - w.y + w.z + w.w) * 0.25f;
            Dd = ( w.x - w.y - w.z + w.w) * 0.25f;
        }
        const float x0 = xs[m.x * PAD + b];
        const float x1 = xs[m.y * PAD + b];
        acc += A + Bc * x0 + Cc * x1 + Dd * (x0 * x1);
    }

    red[g * 64 + b] = acc;
    __syncthreads();

    if ((g & 3) == 0) {
        const int base = (g >> 2) * 256;  // 4 wave-groups per feature
        float s = red[base + b] + red[base + 64 + b] +
                  red[base + 128 + b] + red[base + 192 + b];
        out[b * OUT + o] = s + bias[o];
    }
}

extern "C" void kernel_launch(void* const* d_in, const int* in_sizes, int n_in,
                              void* d_out, int out_size, void* d_ws, size_t ws_size,
                              hipStream_t stream) {
    const float*  input = (const float*)d_in[0];
    const int*    mask  = (const int*)d_in[1];
    const float*  lut   = (const float*)d_in[2];
    const float*  bias  = (const float*)d_in[3];
    float*        out   = (float*)d_out;

    const size_t coeff_bytes = (size_t)T * 4 * sizeof(float);  // 4 MB

    dim3 grid(OUT / 2), block(512);

    if (ws_size >= coeff_bytes) {
        float4* coeff = (float4*)d_ws;
        lut_coeff_kernel<<<dim3(T / 256), dim3(256), 0, stream>>>(
            (const float4*)lut, coeff);
        lut_main_kernel<true><<<grid, block, 0, stream>>>(
            input, mask, coeff, bias, out);
    } else {
        lut_main_kernel<false><<<grid, block, 0, stream>>>(
            input, mask, (const float4*)lut, bias, out);
    }
}